// Round 11
// baseline (470.704 us; speedup 1.0000x reference)
//
#include <hip/hip_runtime.h>

#define D_DIM 1024
#define F_DIM 4096
#define E_NUM 16
#define T_NUM 2048

typedef __bf16 bf16x8 __attribute__((ext_vector_type(8)));
typedef float f32x4 __attribute__((ext_vector_type(4)));

__device__ __forceinline__ unsigned pack2bf(float a, float b) {
  unsigned ua = __builtin_bit_cast(unsigned, a);
  unsigned ub = __builtin_bit_cast(unsigned, b);
  return ((ub + 0x8000u) & 0xffff0000u) | ((ua + 0x8000u) >> 16);
}
__device__ __forceinline__ unsigned short f2bf(float a) {
  unsigned ua = __builtin_bit_cast(unsigned, a);
  return (unsigned short)((ua + 0x8000u) >> 16);
}
__device__ __forceinline__ bf16x8 cvt8(f32x4 a, f32x4 b) {
  bf16x8 r;
  r[0] = (__bf16)a[0]; r[1] = (__bf16)a[1]; r[2] = (__bf16)a[2]; r[3] = (__bf16)a[3];
  r[4] = (__bf16)b[0]; r[5] = (__bf16)b[1]; r[6] = (__bf16)b[2]; r[7] = (__bf16)b[3];
  return r;
}
__device__ __forceinline__ void gload16(const void* g, void* l) {
  __builtin_amdgcn_global_load_lds(
      (const __attribute__((address_space(1))) unsigned*)g,
      (__attribute__((address_space(3))) unsigned*)l, 16, 0, 0);
}

// ---------------- x -> bf16 pre-pass
__global__ __launch_bounds__(256) void moe_xcast(
    const float* __restrict__ x, unsigned short* __restrict__ xbf)
{
  int i = blockIdx.x * 256 + threadIdx.x;
  const f32x4* p = (const f32x4*)x + (size_t)i * 2;
  f32x4 a = p[0], b = p[1];
  uint4 o;
  o.x = pack2bf(a[0], a[1]); o.y = pack2bf(a[2], a[3]);
  o.z = pack2bf(b[0], b[1]); o.w = pack2bf(b[2], b[3]);
  ((uint4*)xbf)[i] = o;
}

// ---------------- router
__global__ __launch_bounds__(256) void moe_router(
    const float* __restrict__ x, const float* __restrict__ gate,
    float* __restrict__ logits_out, int* __restrict__ topi, float* __restrict__ topw)
{
  __shared__ float lg[16][17];
  int tid = threadIdx.x;
  int tbase = blockIdx.x * 16;
  int tt = tid >> 4, e = tid & 15;
  const float4* xr = (const float4*)(x + (size_t)(tbase + tt) * D_DIM);
  const float4* gw = (const float4*)(gate + (size_t)e * D_DIM);
  float acc = 0.f;
  #pragma unroll 4
  for (int k = 0; k < D_DIM / 4; ++k) {
    float4 a = xr[k], b = gw[k];
    acc += a.x * b.x + a.y * b.y + a.z * b.z + a.w * b.w;
  }
  lg[tt][e] = acc;
  logits_out[(size_t)(tbase + tt) * E_NUM + e] = acc;
  __syncthreads();
  if (tid < 16) {
    int t = tid;
    float best = -1e30f; int i0 = 0;
    #pragma unroll
    for (int j = 0; j < 16; ++j) { float v = lg[t][j]; if (v > best) { best = v; i0 = j; } }
    float best1 = -1e30f; int i1 = 0;
    #pragma unroll
    for (int j = 0; j < 16; ++j) { if (j == i0) continue; float v = lg[t][j]; if (v > best1) { best1 = v; i1 = j; } }
    float e1 = __expf(best1 - best);
    float inv = 1.f / (1.f + e1);
    int gt = tbase + t;
    topi[gt * 2]     = i0;  topi[gt * 2 + 1] = i1;
    topw[gt * 2]     = inv; topw[gt * 2 + 1] = e1 * inv;
  }
}

// ---------------- deterministic routing
__global__ __launch_bounds__(1024) void moe_route_build(
    const int* __restrict__ topi,
    int* __restrict__ cnt, int* __restrict__ rowbase,
    int* __restrict__ rowlist, int* __restrict__ rowpos)
{
  __shared__ int scnt[16];
  __shared__ int sbase[17];
  int wave = threadIdx.x >> 6;
  int lane = threadIdx.x & 63;
  int total = 0;
  for (int c = 0; c < (T_NUM * 2) / 64; ++c) {
    int s = c * 64 + lane;
    unsigned long long m = __ballot(topi[s] == wave);
    total += __popcll(m);
  }
  if (lane == 0) scnt[wave] = total;
  __syncthreads();
  if (threadIdx.x == 0) {
    int acc = 0;
    for (int e2 = 0; e2 < 16; ++e2) { sbase[e2] = acc; cnt[e2] = scnt[e2]; acc += scnt[e2]; }
    sbase[16] = acc;
    for (int e2 = 0; e2 <= 16; ++e2) rowbase[e2] = sbase[e2];
  }
  __syncthreads();
  int running = sbase[wave];
  for (int c = 0; c < (T_NUM * 2) / 64; ++c) {
    int s = c * 64 + lane;
    int ei = topi[s];
    unsigned long long m = __ballot(ei == wave);
    if (ei == wave) {
      int pos = running + __popcll(m & ((1ull << lane) - 1ull));
      rowlist[pos] = s;
      rowpos[s] = pos;
    }
    running += __popcll(m);
  }
}

// ---------------- GEMM1: H = silu(x@w1^T) * (x@w3^T)
// 1024 threads (16 waves = 4/SIMD), ONE block/CU. BM=320 BN=128 BK=32, W staged once.
// Wave-split dual matrix: waves 0-7 -> acc1 (w1), waves 8-15 -> acc3 (w3), shared X.
// Per-matrix wave map: 4M x 2N, wave-tile 80x64, acc[5][4]=80 regs.
// 2-deep counted-vmcnt pipeline; per-wave loads: X {2,1} + W1 1 + W3 1 -> vmcnt {4,3}.
// LDS: X 2x20K @0 | W1 2x16K @40960 | W3 2x16K @73728 = 104 KB. Epilogue LDS exchange.
__global__ __launch_bounds__(1024, 1) void moe_gemm1(
    const unsigned short* __restrict__ xbf, const float* __restrict__ w1s, const float* __restrict__ w3s,
    const int* __restrict__ cnt, const int* __restrict__ rowbase, const int* __restrict__ rowlist,
    unsigned short* __restrict__ H)
{
  int nt = blockIdx.x, mt = blockIdx.y, e = blockIdx.z;
  int Ne = cnt[e];
  if (mt * 320 >= Ne) return;
  int rbase = rowbase[e];

  __shared__ char smem[106496];

  int tid = threadIdx.x, lane = tid & 63, wave = tid >> 6;

  // X staging: 20 chunks of 1KB (16 rows x 64B); wave w: chunk w; waves 0-3 also chunk 16+w.
  // source swizzle: slot c4 holds global chunk c4 ^ ((row>>1)&3)
  int nx = (wave < 4) ? 2 : 1;
  const char* px[2];
  unsigned xoff[2];
  #pragma unroll
  for (int it = 0; it < 2; ++it) {
    int ch = wave + it * 16;
    if (ch < 20) {
      int row = ch * 16 + (lane >> 2);
      int lr = mt * 320 + row;
      int tok = (lr < Ne) ? (rowlist[rbase + lr] >> 1) : 0;
      int c4 = (lane & 3) ^ ((row >> 1) & 3);
      px[it] = (const char*)(xbf + (size_t)tok * D_DIM) + c4 * 16;
      xoff[it] = (unsigned)(ch * 1024 + lane * 16);
    } else {
      px[it] = (const char*)xbf;
      xoff[it] = 0;
    }
  }

  // W staging (f32, gload_lds): 16 chunks each (8 rows x 128B); wave w: chunk w.
  const float* w1e = w1s + (size_t)e * F_DIM * D_DIM + (size_t)(nt * 128) * D_DIM;
  const float* w3e = w3s + (size_t)e * F_DIM * D_DIM + (size_t)(nt * 128) * D_DIM;
  int rw = wave * 8 + (lane >> 3);
  int cw = (lane & 7) ^ (rw & 7);
  const char* pw1 = (const char*)(w1e + (size_t)rw * D_DIM) + cw * 16;
  const char* pw3 = (const char*)(w3e + (size_t)rw * D_DIM) + cw * 16;
  unsigned woff = (unsigned)(wave * 1024 + lane * 16);

  // compute mapping: wgrp 0 -> w1, 1 -> w3; within group: 4M x 2N, wave-tile 80x64
  int wgrp = wave >> 3, wl = wave & 7;
  int wm = wl >> 1, wn = wl & 1;
  int lr16 = lane & 15, lq = lane >> 4;

  unsigned offA[5];
  #pragma unroll
  for (int mi = 0; mi < 5; ++mi) {
    int m = wm * 80 + mi * 16 + lr16;
    offA[mi] = (unsigned)(m * 64 + ((lq ^ ((m >> 1) & 3)) * 16));
  }
  unsigned offB[4][2];
  #pragma unroll
  for (int nf = 0; nf < 4; ++nf) {
    int n = wn * 64 + nf * 16 + lr16;
    #pragma unroll
    for (int h = 0; h < 2; ++h)
      offB[nf][h] = (unsigned)(n * 128 + (((lq * 2 + h) ^ (n & 7)) * 16));
  }
  unsigned wbase0 = wgrp ? 73728u : 40960u;

  f32x4 acc[5][4];
  #pragma unroll
  for (int i = 0; i < 5; ++i)
    #pragma unroll
    for (int j = 0; j < 4; ++j) acc[i][j] = {0.f, 0.f, 0.f, 0.f};

  auto STAGE = [&](unsigned bsel, int ks) {
    gload16(px[0] + ks * 64, smem + bsel * 20480u + xoff[0]);
    if (nx == 2) gload16(px[1] + ks * 64, smem + bsel * 20480u + xoff[1]);
    gload16(pw1 + ks * 128, smem + 40960 + bsel * 16384u + woff);
    gload16(pw3 + ks * 128, smem + 73728 + bsel * 16384u + woff);
  };

  STAGE(0, 0);
  unsigned buf = 0;
  for (int ks = 0; ks < 32; ++ks) {
    if (ks < 31) {
      STAGE(buf ^ 1u, ks + 1);
      if (wave < 4) asm volatile("s_waitcnt vmcnt(4)" ::: "memory");
      else          asm volatile("s_waitcnt vmcnt(3)" ::: "memory");
    } else {
      asm volatile("s_waitcnt vmcnt(0)" ::: "memory");
    }
    __builtin_amdgcn_s_barrier();
    unsigned xb = buf * 20480u;
    unsigned wb = wbase0 + buf * 16384u;
    bf16x8 bfr[4];
    #pragma unroll
    for (int nf = 0; nf < 4; ++nf)
      bfr[nf] = cvt8(*(const f32x4*)(smem + wb + offB[nf][0]),
                     *(const f32x4*)(smem + wb + offB[nf][1]));
    #pragma unroll
    for (int mi = 0; mi < 5; ++mi) {
      bf16x8 af = *(const bf16x8*)(smem + xb + offA[mi]);
      #pragma unroll
      for (int nf = 0; nf < 4; ++nf)
        acc[mi][nf] = __builtin_amdgcn_mfma_f32_16x16x32_bf16(af, bfr[nf], acc[mi][nf], 0, 0, 0);
    }
    __builtin_amdgcn_s_barrier();
    buf ^= 1u;
  }

  // epilogue: 4-round LDS exchange (band = 80 rows x 128 cols f32, stride 132)
  float* xch = (float*)smem;
  for (int band = 0; band < 4; ++band) {
    if (wgrp == 0 && wm == band) {
      #pragma unroll
      for (int mi = 0; mi < 5; ++mi) {
        #pragma unroll
        for (int r = 0; r < 4; ++r) {
          int rb = mi * 16 + lq * 4 + r;
          #pragma unroll
          for (int nf = 0; nf < 4; ++nf) {
            int col = wn * 64 + nf * 16 + lr16;
            float a = acc[mi][nf][r];
            xch[rb * 132 + col] = a / (1.f + __expf(-a));
          }
        }
      }
    }
    asm volatile("s_waitcnt lgkmcnt(0)" ::: "memory");
    __builtin_amdgcn_s_barrier();
    if (wgrp == 1 && wm == band) {
      #pragma unroll
      for (int mi = 0; mi < 5; ++mi) {
        #pragma unroll
        for (int r = 0; r < 4; ++r) {
          int rb = mi * 16 + lq * 4 + r;
          int lrow = mt * 320 + band * 80 + rb;
          if (lrow < Ne) {
            size_t hrow = (size_t)(rbase + lrow) * F_DIM;
            #pragma unroll
            for (int nf = 0; nf < 4; ++nf) {
              int col = wn * 64 + nf * 16 + lr16;
              H[hrow + nt * 128 + col] = f2bf(xch[rb * 132 + col] * acc[mi][nf][r]);
            }
          }
        }
      }
    }
    __builtin_amdgcn_s_barrier();
  }
}

// ---------------- GEMM2: Y = H @ w2^T (bf16 out)
// 1024 threads (16 waves = 4/SIMD), 1 block/CU. BM=320 BN=64 BK=64, w2 staged once per nt.
// 16 waves 4M x 4N, wave-tile 80x16, acc[5]=20 regs.
// Per-wave loads: A {3,2} + W2 1 -> vmcnt {4,3}. LDS: A 2x40K @0 | W2 2x16K @81920 = 112 KB.
__global__ __launch_bounds__(1024, 1) void moe_gemm2(
    const unsigned short* __restrict__ H, const float* __restrict__ w2s,
    const int* __restrict__ cnt, const int* __restrict__ rowbase,
    unsigned short* __restrict__ Ybf)
{
  int nt = blockIdx.x, mt = blockIdx.y, e = blockIdx.z;
  int Ne = cnt[e];
  if (mt * 320 >= Ne) return;
  int rbase = rowbase[e];

  __shared__ char smem[114688];

  int tid = threadIdx.x, lane = tid & 63, wave = tid >> 6;

  // A staging: 40 chunks (8 rows x 128B); wave w: chunks w, w+16, (+32 if w<8)
  int na = (wave < 8) ? 3 : 2;
  const char* pa[3];
  unsigned aoff[3];
  #pragma unroll
  for (int it = 0; it < 3; ++it) {
    int ch = wave + it * 16;
    if (ch < 40) {
      int row = ch * 8 + (lane >> 3);
      int grow = mt * 320 + row; if (grow >= Ne) grow = Ne - 1;
      int c8 = (lane & 7) ^ (row & 7);
      pa[it] = (const char*)(H + (size_t)(rbase + grow) * F_DIM) + c8 * 16;
      aoff[it] = (unsigned)(ch * 1024 + lane * 16);
    } else {
      pa[it] = (const char*)H;
      aoff[it] = 0;
    }
  }

  // W2 staging (f32): 16 chunks (4 rows x 256B); wave w: chunk w.
  const float* w2e = w2s + (size_t)e * D_DIM * F_DIM + (size_t)(nt * 64) * F_DIM;
  int rw = wave * 4 + (lane >> 4);
  int cw = (lane & 15) ^ (rw & 7);
  const char* pw2 = (const char*)(w2e + (size_t)rw * F_DIM) + cw * 16;
  unsigned woff = (unsigned)(wave * 1024 + lane * 16);

  // 16 waves = 4M x 4N, wave-tile 80x16
  int wm = wave >> 2, wn = wave & 3;
  int lr16 = lane & 15, lq = lane >> 4;
  int n = wn * 16 + lr16;

  f32x4 acc[5];
  #pragma unroll
  for (int i = 0; i < 5; ++i) acc[i] = {0.f, 0.f, 0.f, 0.f};

  auto STAGE = [&](unsigned bsel, int ks) {
    gload16(pa[0] + ks * 128, smem + bsel * 40960u + aoff[0]);
    gload16(pa[1] + ks * 128, smem + bsel * 40960u + aoff[1]);
    if (na == 3) gload16(pa[2] + ks * 128, smem + bsel * 40960u + aoff[2]);
    gload16(pw2 + ks * 256, smem + 81920 + bsel * 16384u + woff);
  };

  STAGE(0, 0);
  unsigned buf = 0;
  for (int ks = 0; ks < 64; ++ks) {
    if (ks < 63) {
      STAGE(buf ^ 1u, ks + 1);
      if (wave < 8) asm volatile("s_waitcnt vmcnt(4)" ::: "memory");
      else          asm volatile("s_waitcnt vmcnt(3)" ::: "memory");
    } else {
      asm volatile("s_waitcnt vmcnt(0)" ::: "memory");
    }
    __builtin_amdgcn_s_barrier();
    unsigned ab = buf * 40960u;
    unsigned bb = 81920 + buf * 16384u;
    #pragma unroll
    for (int ksub = 0; ksub < 2; ++ksub) {
      unsigned o0 = (unsigned)(n * 256 + (((ksub * 8 + lq * 2 + 0) ^ (n & 7)) * 16));
      unsigned o1 = (unsigned)(n * 256 + (((ksub * 8 + lq * 2 + 1) ^ (n & 7)) * 16));
      bf16x8 bfr = cvt8(*(const f32x4*)(smem + bb + o0), *(const f32x4*)(smem + bb + o1));
      #pragma unroll
      for (int mi = 0; mi < 5; ++mi) {
        int m = wm * 80 + mi * 16 + lr16;
        unsigned off = (unsigned)(m * 128 + (((ksub * 4 + lq) ^ (m & 7)) * 16));
        bf16x8 af = *(const bf16x8*)(smem + ab + off);
        acc[mi] = __builtin_amdgcn_mfma_f32_16x16x32_bf16(af, bfr, acc[mi], 0, 0, 0);
      }
    }
    __builtin_amdgcn_s_barrier();
    buf ^= 1u;
  }

  #pragma unroll
  for (int mi = 0; mi < 5; ++mi) {
    int mb = wm * 80 + mi * 16 + lq * 4;
    #pragma unroll
    for (int r = 0; r < 4; ++r) {
      int lrow = mt * 320 + mb + r;
      if (lrow < Ne) {
        size_t yrow = (size_t)(rbase + lrow) * D_DIM;
        Ybf[yrow + nt * 64 + n] = f2bf(acc[mi][r]);
      }
    }
  }
}

// ---------------- combine
__global__ __launch_bounds__(128) void moe_combine(
    const unsigned short* __restrict__ Ybf, const int* __restrict__ rowpos,
    const float* __restrict__ topw, float* __restrict__ out)
{
  int t = blockIdx.x, tid = threadIdx.x;
  int r0 = rowpos[t * 2], r1 = rowpos[t * 2 + 1];
  float p0 = topw[t * 2], p1 = topw[t * 2 + 1];
  uint4 a = ((const uint4*)(Ybf + (size_t)r0 * D_DIM))[tid];
  uint4 b = ((const uint4*)(Ybf + (size_t)r1 * D_DIM))[tid];
  float4 o0, o1;
  #define LO(u) __builtin_bit_cast(float, (unsigned)((u) << 16))
  #define HI(u) __builtin_bit_cast(float, (unsigned)((u) & 0xffff0000u))
  o0.x = p0 * LO(a.x) + p1 * LO(b.x);  o0.y = p0 * HI(a.x) + p1 * HI(b.x);
  o0.z = p0 * LO(a.y) + p1 * LO(b.y);  o0.w = p0 * HI(a.y) + p1 * HI(b.y);
  o1.x = p0 * LO(a.z) + p1 * LO(b.z);  o1.y = p0 * HI(a.z) + p1 * HI(b.z);
  o1.z = p0 * LO(a.w) + p1 * LO(b.w);  o1.w = p0 * HI(a.w) + p1 * HI(b.w);
  #undef LO
  #undef HI
  float4* orow = (float4*)(out + (size_t)t * D_DIM);
  orow[tid * 2]     = o0;
  orow[tid * 2 + 1] = o1;
}

extern "C" void kernel_launch(void* const* d_in, const int* in_sizes, int n_in,
                              void* d_out, int out_size, void* d_ws, size_t ws_size,
                              hipStream_t stream) {
  const float* x    = (const float*)d_in[0];
  const float* gate = (const float*)d_in[1];
  const float* w1   = (const float*)d_in[2];
  const float* w2   = (const float*)d_in[3];
  const float* w3   = (const float*)d_in[4];
  float* out    = (float*)d_out;
  float* logits = out + (size_t)T_NUM * D_DIM;

  char* ws = (char*)d_ws;
  int*   cnt     = (int*)(ws + 0);
  int*   rowbase = (int*)(ws + 64);
  int*   topi    = (int*)(ws + 1024);
  float* topw    = (float*)(ws + 1024 + 16384);
  int*   rowlist = (int*)(ws + 1024 + 32768);
  int*   rowpos  = (int*)(ws + 1024 + 49152);
  unsigned short* H   = (unsigned short*)(ws + 131072);                      // 32 MB
  unsigned short* Ybf = (unsigned short*)(ws + 131072 + 33554432);           // 8 MB
  unsigned short* xbf = (unsigned short*)(ws + 131072 + 33554432 + 8388608); // 4 MB

  moe_xcast<<<(T_NUM * D_DIM) / (256 * 8), 256, 0, stream>>>(x, xbf);
  moe_router<<<T_NUM / 16, 256, 0, stream>>>(x, gate, logits, topi, topw);
  moe_route_build<<<1, 1024, 0, stream>>>(topi, cnt, rowbase, rowlist, rowpos);
  moe_gemm1<<<dim3(32, 13, 16), 1024, 0, stream>>>(xbf, w1, w3, cnt, rowbase, rowlist, H);
  moe_gemm2<<<dim3(16, 13, 16), 1024, 0, stream>>>(H, w2, cnt, rowbase, Ybf);
  moe_combine<<<T_NUM, 128, 0, stream>>>(Ybf, rowpos, topw, out);
}

// Round 12
// 346.252 us; speedup vs baseline: 1.3594x; 1.3594x over previous
//
#include <hip/hip_runtime.h>

#define D_DIM 1024
#define F_DIM 4096
#define E_NUM 16
#define T_NUM 2048

typedef __bf16 bf16x8 __attribute__((ext_vector_type(8)));
typedef float f32x4 __attribute__((ext_vector_type(4)));

__device__ __forceinline__ unsigned pack2bf(float a, float b) {
  unsigned ua = __builtin_bit_cast(unsigned, a);
  unsigned ub = __builtin_bit_cast(unsigned, b);
  return ((ub + 0x8000u) & 0xffff0000u) | ((ua + 0x8000u) >> 16);
}
__device__ __forceinline__ unsigned short f2bf(float a) {
  unsigned ua = __builtin_bit_cast(unsigned, a);
  return (unsigned short)((ua + 0x8000u) >> 16);
}
__device__ __forceinline__ bf16x8 cvt8(f32x4 a, f32x4 b) {
  bf16x8 r;
  r[0] = (__bf16)a[0]; r[1] = (__bf16)a[1]; r[2] = (__bf16)a[2]; r[3] = (__bf16)a[3];
  r[4] = (__bf16)b[0]; r[5] = (__bf16)b[1]; r[6] = (__bf16)b[2]; r[7] = (__bf16)b[3];
  return r;
}
__device__ __forceinline__ void gload16(const void* g, void* l) {
  __builtin_amdgcn_global_load_lds(
      (const __attribute__((address_space(1))) unsigned*)g,
      (__attribute__((address_space(3))) unsigned*)l, 16, 0, 0);
}

// ---------------- router
__global__ __launch_bounds__(256) void moe_router(
    const float* __restrict__ x, const float* __restrict__ gate,
    float* __restrict__ logits_out, int* __restrict__ topi, float* __restrict__ topw)
{
  __shared__ float lg[16][17];
  int tid = threadIdx.x;
  int tbase = blockIdx.x * 16;
  int tt = tid >> 4, e = tid & 15;
  const float4* xr = (const float4*)(x + (size_t)(tbase + tt) * D_DIM);
  const float4* gw = (const float4*)(gate + (size_t)e * D_DIM);
  float acc = 0.f;
  #pragma unroll 4
  for (int k = 0; k < D_DIM / 4; ++k) {
    float4 a = xr[k], b = gw[k];
    acc += a.x * b.x + a.y * b.y + a.z * b.z + a.w * b.w;
  }
  lg[tt][e] = acc;
  logits_out[(size_t)(tbase + tt) * E_NUM + e] = acc;
  __syncthreads();
  if (tid < 16) {
    int t = tid;
    float best = -1e30f; int i0 = 0;
    #pragma unroll
    for (int j = 0; j < 16; ++j) { float v = lg[t][j]; if (v > best) { best = v; i0 = j; } }
    float best1 = -1e30f; int i1 = 0;
    #pragma unroll
    for (int j = 0; j < 16; ++j) { if (j == i0) continue; float v = lg[t][j]; if (v > best1) { best1 = v; i1 = j; } }
    float e1 = __expf(best1 - best);
    float inv = 1.f / (1.f + e1);
    int gt = tbase + t;
    topi[gt * 2]     = i0;  topi[gt * 2 + 1] = i1;
    topw[gt * 2]     = inv; topw[gt * 2 + 1] = e1 * inv;
  }
}

// ---------------- deterministic routing
__global__ __launch_bounds__(1024) void moe_route_build(
    const int* __restrict__ topi,
    int* __restrict__ cnt, int* __restrict__ rowbase,
    int* __restrict__ rowlist, int* __restrict__ rowpos)
{
  __shared__ int scnt[16];
  __shared__ int sbase[17];
  int wave = threadIdx.x >> 6;
  int lane = threadIdx.x & 63;
  int total = 0;
  for (int c = 0; c < (T_NUM * 2) / 64; ++c) {
    int s = c * 64 + lane;
    unsigned long long m = __ballot(topi[s] == wave);
    total += __popcll(m);
  }
  if (lane == 0) scnt[wave] = total;
  __syncthreads();
  if (threadIdx.x == 0) {
    int acc = 0;
    for (int e2 = 0; e2 < 16; ++e2) { sbase[e2] = acc; cnt[e2] = scnt[e2]; acc += scnt[e2]; }
    sbase[16] = acc;
    for (int e2 = 0; e2 <= 16; ++e2) rowbase[e2] = sbase[e2];
  }
  __syncthreads();
  int running = sbase[wave];
  for (int c = 0; c < (T_NUM * 2) / 64; ++c) {
    int s = c * 64 + lane;
    int ei = topi[s];
    unsigned long long m = __ballot(ei == wave);
    if (ei == wave) {
      int pos = running + __popcll(m & ((1ull << lane) - 1ull));
      rowlist[pos] = s;
      rowpos[s] = pos;
    }
    running += __popcll(m);
  }
}

// ---------------- X gather: xg[pos] = bf16(x[rowlist[pos]>>1]) -- compacted, contiguous rows
__global__ __launch_bounds__(256) void moe_gather(
    const float* __restrict__ x, const int* __restrict__ rowlist,
    const int* __restrict__ rowbase, unsigned short* __restrict__ xg)
{
  int pos = blockIdx.x;
  int total = rowbase[16];
  int tok = (pos < total) ? (rowlist[pos] >> 1) : 0;
  f32x4 v = ((const f32x4*)(x + (size_t)tok * D_DIM))[threadIdx.x];
  ((uint2*)(xg + (size_t)pos * D_DIM))[threadIdx.x] =
      make_uint2(pack2bf(v[0], v[1]), pack2bf(v[2], v[3]));
}

// ---------------- GEMM1: H = silu(x@w1^T) * (x@w3^T)
// BM=320 BN=128 BK=32, 512 thr, 1 block/CU. X from CONTIGUOUS xg (compacted).
// W staged exactly once. 2-deep counted-vmcnt pipeline, per-wave counts {7,6}.
// LDS: X 2x20K @0 | W1 2x16K @40960 | W3 2x16K @73728 = 104 KB.
__global__ __launch_bounds__(512, 2) void moe_gemm1(
    const unsigned short* __restrict__ xg, const float* __restrict__ w1s, const float* __restrict__ w3s,
    const int* __restrict__ cnt, const int* __restrict__ rowbase,
    unsigned short* __restrict__ H)
{
  int nt = blockIdx.x, mt = blockIdx.y, e = blockIdx.z;
  int Ne = cnt[e];
  if (mt * 320 >= Ne) return;
  int rbase = rowbase[e];

  __shared__ char smem[106496];

  int tid = threadIdx.x, lane = tid & 63, wave = tid >> 6;

  // X staging: 20 chunks of 1KB (16 contiguous xg rows x 64B); wave w: {w, w+8, w+16 if w<4}
  // source swizzle: LDS slot s holds global k-chunk s^((row>>1)&3)
  const char* px[3];
  unsigned xoff[3];
  #pragma unroll
  for (int it = 0; it < 3; ++it) {
    int ch = wave + it * 8;
    if (ch < 20) {
      int row = ch * 16 + (lane >> 2);
      int slot = (lane & 3) ^ ((row >> 1) & 3);
      px[it] = (const char*)(xg + (size_t)(rbase + mt * 320 + row) * D_DIM) + slot * 16;
      xoff[it] = (unsigned)(ch * 1024 + lane * 16);
    } else {
      px[it] = (const char*)xg;
      xoff[it] = 0;
    }
  }

  // W staging: 16 chunks (8 rows x 128B); wave owns 2w, 2w+1
  const float* w1e = w1s + (size_t)e * F_DIM * D_DIM + (size_t)(nt * 128) * D_DIM;
  const float* w3e = w3s + (size_t)e * F_DIM * D_DIM + (size_t)(nt * 128) * D_DIM;
  const char* p1[2]; const char* p3[2];
  #pragma unroll
  for (int it = 0; it < 2; ++it) {
    int r = (wave * 2 + it) * 8 + (lane >> 3);
    int c = (lane & 7) ^ (r & 7);
    p1[it] = (const char*)(w1e + (size_t)r * D_DIM) + c * 16;
    p3[it] = (const char*)(w3e + (size_t)r * D_DIM) + c * 16;
  }

  // wave map: 4M x 2N, wave-tile 80x64
  int wm = wave >> 1, wn = wave & 1;
  int lr16 = lane & 15, lq = lane >> 4;

  unsigned offA[5];
  #pragma unroll
  for (int mi = 0; mi < 5; ++mi) {
    int m = wm * 80 + mi * 16 + lr16;
    offA[mi] = (unsigned)(m * 64 + ((lq ^ ((m >> 1) & 3)) * 16));
  }
  unsigned offB[4][2];
  #pragma unroll
  for (int ni = 0; ni < 4; ++ni) {
    int n = wn * 64 + ni * 16 + lr16;
    #pragma unroll
    for (int h = 0; h < 2; ++h)
      offB[ni][h] = (unsigned)(n * 128 + (((lq * 2 + h) ^ (n & 7)) * 16));
  }

  unsigned wdst = (unsigned)((wave * 2) * 1024 + lane * 16);

  f32x4 acc1[5][4], acc3[5][4];
  #pragma unroll
  for (int i = 0; i < 5; ++i)
    #pragma unroll
    for (int j = 0; j < 4; ++j) { acc1[i][j] = {0.f,0.f,0.f,0.f}; acc3[i][j] = {0.f,0.f,0.f,0.f}; }

  auto STAGE = [&](unsigned bsel, int ks) {
    gload16(px[0] + ks * 64, smem + bsel * 20480u + xoff[0]);
    gload16(px[1] + ks * 64, smem + bsel * 20480u + xoff[1]);
    if (wave < 4) gload16(px[2] + ks * 64, smem + bsel * 20480u + xoff[2]);
    #pragma unroll
    for (int it = 0; it < 2; ++it) {
      gload16(p1[it] + ks * 128, smem + 40960 + bsel * 16384u + wdst + it * 1024);
      gload16(p3[it] + ks * 128, smem + 73728 + bsel * 16384u + wdst + it * 1024);
    }
  };

  STAGE(0, 0);
  unsigned buf = 0;
  for (int ks = 0; ks < 32; ++ks) {
    if (ks < 31) {
      STAGE(buf ^ 1u, ks + 1);
      if (wave < 4) asm volatile("s_waitcnt vmcnt(7)" ::: "memory");
      else          asm volatile("s_waitcnt vmcnt(6)" ::: "memory");
    } else {
      asm volatile("s_waitcnt vmcnt(0)" ::: "memory");
    }
    __builtin_amdgcn_s_barrier();
    unsigned xb = buf * 20480u;
    unsigned w1b = 40960 + buf * 16384u;
    unsigned w3b = 73728 + buf * 16384u;
    bf16x8 af[5];
    #pragma unroll
    for (int mi = 0; mi < 5; ++mi)
      af[mi] = *(const bf16x8*)(smem + xb + offA[mi]);
    #pragma unroll
    for (int ni = 0; ni < 4; ++ni) {
      bf16x8 b1 = cvt8(*(const f32x4*)(smem + w1b + offB[ni][0]),
                       *(const f32x4*)(smem + w1b + offB[ni][1]));
      bf16x8 b3 = cvt8(*(const f32x4*)(smem + w3b + offB[ni][0]),
                       *(const f32x4*)(smem + w3b + offB[ni][1]));
      #pragma unroll
      for (int mi = 0; mi < 5; ++mi) {
        acc1[mi][ni] = __builtin_amdgcn_mfma_f32_16x16x32_bf16(af[mi], b1, acc1[mi][ni], 0, 0, 0);
        acc3[mi][ni] = __builtin_amdgcn_mfma_f32_16x16x32_bf16(af[mi], b3, acc3[mi][ni], 0, 0, 0);
      }
    }
    __builtin_amdgcn_s_barrier();
    buf ^= 1u;
  }

  #pragma unroll
  for (int mi = 0; mi < 5; ++mi) {
    int mb = wm * 80 + mi * 16 + lq * 4;
    #pragma unroll
    for (int r = 0; r < 4; ++r) {
      int lrow = mt * 320 + mb + r;
      if (lrow < Ne) {
        size_t hrow = (size_t)(rbase + lrow) * F_DIM;
        #pragma unroll
        for (int ni = 0; ni < 4; ++ni) {
          int f = nt * 128 + wn * 64 + ni * 16 + lr16;
          float a1v = acc1[mi][ni][r];
          float a3v = acc3[mi][ni][r];
          float hv = (a1v / (1.f + __expf(-a1v))) * a3v;
          H[hrow + f] = f2bf(hv);
        }
      }
    }
  }
}

// ---------------- GEMM2: Y = H @ w2^T (bf16 out)
// BM=320 BN=128 BK=64, 512 thr, 1 block/CU. H re-staged only 8x (was 16x).
// Uniform 9 loads/wave (5 A + 4 B), vmcnt(9).
// LDS: A 2x40K @0 | B 2x32K @81920 = 144 KB.
__global__ __launch_bounds__(512, 2) void moe_gemm2(
    const unsigned short* __restrict__ H, const float* __restrict__ w2s,
    const int* __restrict__ cnt, const int* __restrict__ rowbase,
    unsigned short* __restrict__ Ybf)
{
  int nt = blockIdx.x, mt = blockIdx.y, e = blockIdx.z;
  int Ne = cnt[e];
  if (mt * 320 >= Ne) return;
  int rbase = rowbase[e];

  __shared__ char smem[147456];

  int tid = threadIdx.x, lane = tid & 63, wave = tid >> 6;

  // A staging: 40 chunks (8 rows x 128B); wave w: {w, w+8, w+16, w+24, w+32}
  const char* pa[5];
  unsigned aoff[5];
  #pragma unroll
  for (int it = 0; it < 5; ++it) {
    int ch = wave + it * 8;
    int row = ch * 8 + (lane >> 3);
    int grow = mt * 320 + row; if (grow >= Ne) grow = Ne - 1;
    int c8 = (lane & 7) ^ (row & 7);
    pa[it] = (const char*)(H + (size_t)(rbase + grow) * F_DIM) + c8 * 16;
    aoff[it] = (unsigned)(ch * 1024 + lane * 16);
  }

  // B staging: 32 chunks (4 rows x 256B); wave w: {w, w+8, w+16, w+24}
  const float* w2e = w2s + (size_t)e * D_DIM * F_DIM + (size_t)(nt * 128) * F_DIM;
  const char* pb[4];
  unsigned boff[4];
  #pragma unroll
  for (int it = 0; it < 4; ++it) {
    int ch = wave + it * 8;
    int row = ch * 4 + (lane >> 4);
    int c = (lane & 15) ^ (row & 7);
    pb[it] = (const char*)(w2e + (size_t)row * F_DIM) + c * 16;
    boff[it] = (unsigned)(ch * 1024 + lane * 16);
  }

  // wave map: 4M x 2N, wave-tile 80x64
  int wm = wave >> 1, wn = wave & 1;
  int lr16 = lane & 15, lq = lane >> 4;

  unsigned offB[4][2];
  #pragma unroll
  for (int ni = 0; ni < 4; ++ni) {
    int n = wn * 64 + ni * 16 + lr16;
    #pragma unroll
    for (int h = 0; h < 2; ++h)
      offB[ni][h] = (unsigned)(n * 256 + (((lq * 2 + h) ^ (n & 7)) * 16));   // h advanced by ksub*8 later
  }

  f32x4 acc[5][4];
  #pragma unroll
  for (int i = 0; i < 5; ++i)
    #pragma unroll
    for (int j = 0; j < 4; ++j) acc[i][j] = {0.f, 0.f, 0.f, 0.f};

  auto STAGE = [&](unsigned bsel, int ks) {
    #pragma unroll
    for (int it = 0; it < 5; ++it)
      gload16(pa[it] + ks * 128, smem + bsel * 40960u + aoff[it]);
    #pragma unroll
    for (int it = 0; it < 4; ++it)
      gload16(pb[it] + ks * 256, smem + 81920 + bsel * 32768u + boff[it]);
  };

  STAGE(0, 0);
  unsigned buf = 0;
  for (int ks = 0; ks < 64; ++ks) {
    if (ks < 63) {
      STAGE(buf ^ 1u, ks + 1);
      asm volatile("s_waitcnt vmcnt(9)" ::: "memory");
    } else {
      asm volatile("s_waitcnt vmcnt(0)" ::: "memory");
    }
    __builtin_amdgcn_s_barrier();
    unsigned ab = buf * 40960u;
    unsigned bb = 81920 + buf * 32768u;
    #pragma unroll
    for (int ksub = 0; ksub < 2; ++ksub) {
      bf16x8 bfr[4];
      #pragma unroll
      for (int ni = 0; ni < 4; ++ni) {
        int n = wn * 64 + ni * 16 + lr16;
        unsigned o0 = (unsigned)(n * 256 + (((ksub * 8 + lq * 2 + 0) ^ (n & 7)) * 16));
        unsigned o1 = (unsigned)(n * 256 + (((ksub * 8 + lq * 2 + 1) ^ (n & 7)) * 16));
        bfr[ni] = cvt8(*(const f32x4*)(smem + bb + o0), *(const f32x4*)(smem + bb + o1));
      }
      #pragma unroll
      for (int mi = 0; mi < 5; ++mi) {
        int m = wm * 80 + mi * 16 + lr16;
        unsigned off = (unsigned)(m * 128 + (((ksub * 4 + lq) ^ (m & 7)) * 16));
        bf16x8 af = *(const bf16x8*)(smem + ab + off);
        #pragma unroll
        for (int ni = 0; ni < 4; ++ni)
          acc[mi][ni] = __builtin_amdgcn_mfma_f32_16x16x32_bf16(af, bfr[ni], acc[mi][ni], 0, 0, 0);
      }
    }
    __builtin_amdgcn_s_barrier();
    buf ^= 1u;
  }

  #pragma unroll
  for (int mi = 0; mi < 5; ++mi) {
    int mb = wm * 80 + mi * 16 + lq * 4;
    #pragma unroll
    for (int r = 0; r < 4; ++r) {
      int lrow = mt * 320 + mb + r;
      if (lrow < Ne) {
        size_t yrow = (size_t)(rbase + lrow) * D_DIM;
        #pragma unroll
        for (int ni = 0; ni < 4; ++ni) {
          int d = nt * 128 + wn * 64 + ni * 16 + lr16;
          Ybf[yrow + d] = f2bf(acc[mi][ni][r]);
        }
      }
    }
  }
}

// ---------------- combine
__global__ __launch_bounds__(128) void moe_combine(
    const unsigned short* __restrict__ Ybf, const int* __restrict__ rowpos,
    const float* __restrict__ topw, float* __restrict__ out)
{
  int t = blockIdx.x, tid = threadIdx.x;
  int r0 = rowpos[t * 2], r1 = rowpos[t * 2 + 1];
  float p0 = topw[t * 2], p1 = topw[t * 2 + 1];
  uint4 a = ((const uint4*)(Ybf + (size_t)r0 * D_DIM))[tid];
  uint4 b = ((const uint4*)(Ybf + (size_t)r1 * D_DIM))[tid];
  float4 o0, o1;
  #define LO(u) __builtin_bit_cast(float, (unsigned)((u) << 16))
  #define HI(u) __builtin_bit_cast(float, (unsigned)((u) & 0xffff0000u))
  o0.x = p0 * LO(a.x) + p1 * LO(b.x);  o0.y = p0 * HI(a.x) + p1 * HI(b.x);
  o0.z = p0 * LO(a.y) + p1 * LO(b.y);  o0.w = p0 * HI(a.y) + p1 * HI(b.y);
  o1.x = p0 * LO(a.z) + p1 * LO(b.z);  o1.y = p0 * HI(a.z) + p1 * HI(b.z);
  o1.z = p0 * LO(a.w) + p1 * LO(b.w);  o1.w = p0 * HI(a.w) + p1 * HI(b.w);
  #undef LO
  #undef HI
  float4* orow = (float4*)(out + (size_t)t * D_DIM);
  orow[tid * 2]     = o0;
  orow[tid * 2 + 1] = o1;
}

extern "C" void kernel_launch(void* const* d_in, const int* in_sizes, int n_in,
                              void* d_out, int out_size, void* d_ws, size_t ws_size,
                              hipStream_t stream) {
  const float* x    = (const float*)d_in[0];
  const float* gate = (const float*)d_in[1];
  const float* w1   = (const float*)d_in[2];
  const float* w2   = (const float*)d_in[3];
  const float* w3   = (const float*)d_in[4];
  float* out    = (float*)d_out;
  float* logits = out + (size_t)T_NUM * D_DIM;

  char* ws = (char*)d_ws;
  int*   cnt     = (int*)(ws + 0);
  int*   rowbase = (int*)(ws + 64);
  int*   topi    = (int*)(ws + 1024);
  float* topw    = (float*)(ws + 1024 + 16384);
  int*   rowlist = (int*)(ws + 1024 + 32768);
  int*   rowpos  = (int*)(ws + 1024 + 49152);
  unsigned short* H  = (unsigned short*)(ws + 131072);                 // 32 MB
  // xg (6144 rows, 12.6 MB) and Ybf (4096 rows, 8 MB) share one region:
  // xg is dead before gemm2 writes Ybf.
  unsigned short* xg  = (unsigned short*)(ws + 131072 + 33554432);
  unsigned short* Ybf = xg;

  moe_router<<<T_NUM / 16, 256, 0, stream>>>(x, gate, logits, topi, topw);
  moe_route_build<<<1, 1024, 0, stream>>>(topi, cnt, rowbase, rowlist, rowpos);
  moe_gather<<<6144, 256, 0, stream>>>(x, rowlist, rowbase, xg);
  moe_gemm1<<<dim3(32, 2, 16), 512, 0, stream>>>(xg, w1, w3, cnt, rowbase, H);
  moe_gemm2<<<dim3(8, 2, 16), 512, 0, stream>>>(H, w2, cnt, rowbase, Ybf);
  moe_combine<<<T_NUM, 128, 0, stream>>>(Ybf, rowpos, topw, out);
}

// Round 13
// 322.049 us; speedup vs baseline: 1.4616x; 1.0752x over previous
//
#include <hip/hip_runtime.h>

#define D_DIM 1024
#define F_DIM 4096
#define E_NUM 16
#define T_NUM 2048

typedef __bf16 bf16x8 __attribute__((ext_vector_type(8)));
typedef float f32x4 __attribute__((ext_vector_type(4)));

__device__ __forceinline__ unsigned pack2bf(float a, float b) {
  unsigned ua = __builtin_bit_cast(unsigned, a);
  unsigned ub = __builtin_bit_cast(unsigned, b);
  return ((ub + 0x8000u) & 0xffff0000u) | ((ua + 0x8000u) >> 16);
}
__device__ __forceinline__ unsigned short f2bf(float a) {
  unsigned ua = __builtin_bit_cast(unsigned, a);
  return (unsigned short)((ua + 0x8000u) >> 16);
}
__device__ __forceinline__ bf16x8 cvt8(f32x4 a, f32x4 b) {
  bf16x8 r;
  r[0] = (__bf16)a[0]; r[1] = (__bf16)a[1]; r[2] = (__bf16)a[2]; r[3] = (__bf16)a[3];
  r[4] = (__bf16)b[0]; r[5] = (__bf16)b[1]; r[6] = (__bf16)b[2]; r[7] = (__bf16)b[3];
  return r;
}
__device__ __forceinline__ void gload16(const void* g, void* l) {
  __builtin_amdgcn_global_load_lds(
      (const __attribute__((address_space(1))) unsigned*)g,
      (__attribute__((address_space(3))) unsigned*)l, 16, 0, 0);
}

// ---------------- router
__global__ __launch_bounds__(256) void moe_router(
    const float* __restrict__ x, const float* __restrict__ gate,
    float* __restrict__ logits_out, int* __restrict__ topi, float* __restrict__ topw)
{
  __shared__ float lg[16][17];
  int tid = threadIdx.x;
  int tbase = blockIdx.x * 16;
  int tt = tid >> 4, e = tid & 15;
  const float4* xr = (const float4*)(x + (size_t)(tbase + tt) * D_DIM);
  const float4* gw = (const float4*)(gate + (size_t)e * D_DIM);
  float acc = 0.f;
  #pragma unroll 4
  for (int k = 0; k < D_DIM / 4; ++k) {
    float4 a = xr[k], b = gw[k];
    acc += a.x * b.x + a.y * b.y + a.z * b.z + a.w * b.w;
  }
  lg[tt][e] = acc;
  logits_out[(size_t)(tbase + tt) * E_NUM + e] = acc;
  __syncthreads();
  if (tid < 16) {
    int t = tid;
    float best = -1e30f; int i0 = 0;
    #pragma unroll
    for (int j = 0; j < 16; ++j) { float v = lg[t][j]; if (v > best) { best = v; i0 = j; } }
    float best1 = -1e30f; int i1 = 0;
    #pragma unroll
    for (int j = 0; j < 16; ++j) { if (j == i0) continue; float v = lg[t][j]; if (v > best1) { best1 = v; i1 = j; } }
    float e1 = __expf(best1 - best);
    float inv = 1.f / (1.f + e1);
    int gt = tbase + t;
    topi[gt * 2]     = i0;  topi[gt * 2 + 1] = i1;
    topw[gt * 2]     = inv; topw[gt * 2 + 1] = e1 * inv;
  }
}

// ---------------- deterministic routing
__global__ __launch_bounds__(1024) void moe_route_build(
    const int* __restrict__ topi,
    int* __restrict__ cnt, int* __restrict__ rowbase,
    int* __restrict__ rowlist, int* __restrict__ rowpos)
{
  __shared__ int scnt[16];
  __shared__ int sbase[17];
  int wave = threadIdx.x >> 6;
  int lane = threadIdx.x & 63;
  int total = 0;
  for (int c = 0; c < (T_NUM * 2) / 64; ++c) {
    int s = c * 64 + lane;
    unsigned long long m = __ballot(topi[s] == wave);
    total += __popcll(m);
  }
  if (lane == 0) scnt[wave] = total;
  __syncthreads();
  if (threadIdx.x == 0) {
    int acc = 0;
    for (int e2 = 0; e2 < 16; ++e2) { sbase[e2] = acc; cnt[e2] = scnt[e2]; acc += scnt[e2]; }
    sbase[16] = acc;
    for (int e2 = 0; e2 <= 16; ++e2) rowbase[e2] = sbase[e2];
  }
  __syncthreads();
  int running = sbase[wave];
  for (int c = 0; c < (T_NUM * 2) / 64; ++c) {
    int s = c * 64 + lane;
    int ei = topi[s];
    unsigned long long m = __ballot(ei == wave);
    if (ei == wave) {
      int pos = running + __popcll(m & ((1ull << lane) - 1ull));
      rowlist[pos] = s;
      rowpos[s] = pos;
    }
    running += __popcll(m);
  }
}

// ---------------- X gather: xg[pos] = bf16(x[rowlist[pos]>>1]) -- compacted, contiguous rows
__global__ __launch_bounds__(256) void moe_gather(
    const float* __restrict__ x, const int* __restrict__ rowlist,
    const int* __restrict__ rowbase, unsigned short* __restrict__ xg)
{
  int pos = blockIdx.x;
  int total = rowbase[16];
  int tok = (pos < total) ? (rowlist[pos] >> 1) : 0;
  f32x4 v = ((const f32x4*)(x + (size_t)tok * D_DIM))[threadIdx.x];
  ((uint2*)(xg + (size_t)pos * D_DIM))[threadIdx.x] =
      make_uint2(pack2bf(v[0], v[1]), pack2bf(v[2], v[3]));
}

// ---------------- GEMM1: H = silu(x@w1^T) * (x@w3^T)
// BM=320 BN=128 BK=32, 512 thr, 1 block/CU. X from CONTIGUOUS xg (compacted).
// XCD-PINNED 1D grid (1024): xcd=bid&7, sub=bid>>3; e=xcd*2+(sub>>6); nt=sub&31; mt=(sub>>5)&1.
// First dispatch cohort = all 32 nt-blocks of one expert per XCD -> X L2-resident.
// W staged exactly once. 2-deep counted-vmcnt pipeline, per-wave counts {7,6}.
// LDS: X 2x20K @0 | W1 2x16K @40960 | W3 2x16K @73728 = 104 KB.
__global__ __launch_bounds__(512, 2) void moe_gemm1(
    const unsigned short* __restrict__ xg, const float* __restrict__ w1s, const float* __restrict__ w3s,
    const int* __restrict__ cnt, const int* __restrict__ rowbase,
    unsigned short* __restrict__ H)
{
  int bid = blockIdx.x;
  int xcd = bid & 7, sub = bid >> 3;
  int e  = xcd * 2 + (sub >> 6);
  int nt = sub & 31;
  int mt = (sub >> 5) & 1;
  int Ne = cnt[e];
  if (mt * 320 >= Ne) return;
  int rbase = rowbase[e];

  __shared__ char smem[106496];

  int tid = threadIdx.x, lane = tid & 63, wave = tid >> 6;

  // X staging: 20 chunks of 1KB (16 contiguous xg rows x 64B); wave w: {w, w+8, w+16 if w<4}
  // source swizzle: LDS slot s holds global k-chunk s^((row>>1)&3)
  const char* px[3];
  unsigned xoff[3];
  #pragma unroll
  for (int it = 0; it < 3; ++it) {
    int ch = wave + it * 8;
    if (ch < 20) {
      int row = ch * 16 + (lane >> 2);
      int slot = (lane & 3) ^ ((row >> 1) & 3);
      px[it] = (const char*)(xg + (size_t)(rbase + mt * 320 + row) * D_DIM) + slot * 16;
      xoff[it] = (unsigned)(ch * 1024 + lane * 16);
    } else {
      px[it] = (const char*)xg;
      xoff[it] = 0;
    }
  }

  // W staging: 16 chunks (8 rows x 128B); wave owns 2w, 2w+1
  const float* w1e = w1s + (size_t)e * F_DIM * D_DIM + (size_t)(nt * 128) * D_DIM;
  const float* w3e = w3s + (size_t)e * F_DIM * D_DIM + (size_t)(nt * 128) * D_DIM;
  const char* p1[2]; const char* p3[2];
  #pragma unroll
  for (int it = 0; it < 2; ++it) {
    int r = (wave * 2 + it) * 8 + (lane >> 3);
    int c = (lane & 7) ^ (r & 7);
    p1[it] = (const char*)(w1e + (size_t)r * D_DIM) + c * 16;
    p3[it] = (const char*)(w3e + (size_t)r * D_DIM) + c * 16;
  }

  // wave map: 4M x 2N, wave-tile 80x64
  int wm = wave >> 1, wn = wave & 1;
  int lr16 = lane & 15, lq = lane >> 4;

  unsigned offA[5];
  #pragma unroll
  for (int mi = 0; mi < 5; ++mi) {
    int m = wm * 80 + mi * 16 + lr16;
    offA[mi] = (unsigned)(m * 64 + ((lq ^ ((m >> 1) & 3)) * 16));
  }
  unsigned offB[4][2];
  #pragma unroll
  for (int ni = 0; ni < 4; ++ni) {
    int n = wn * 64 + ni * 16 + lr16;
    #pragma unroll
    for (int h = 0; h < 2; ++h)
      offB[ni][h] = (unsigned)(n * 128 + (((lq * 2 + h) ^ (n & 7)) * 16));
  }

  unsigned wdst = (unsigned)((wave * 2) * 1024 + lane * 16);

  f32x4 acc1[5][4], acc3[5][4];
  #pragma unroll
  for (int i = 0; i < 5; ++i)
    #pragma unroll
    for (int j = 0; j < 4; ++j) { acc1[i][j] = {0.f,0.f,0.f,0.f}; acc3[i][j] = {0.f,0.f,0.f,0.f}; }

  auto STAGE = [&](unsigned bsel, int ks) {
    gload16(px[0] + ks * 64, smem + bsel * 20480u + xoff[0]);
    gload16(px[1] + ks * 64, smem + bsel * 20480u + xoff[1]);
    if (wave < 4) gload16(px[2] + ks * 64, smem + bsel * 20480u + xoff[2]);
    #pragma unroll
    for (int it = 0; it < 2; ++it) {
      gload16(p1[it] + ks * 128, smem + 40960 + bsel * 16384u + wdst + it * 1024);
      gload16(p3[it] + ks * 128, smem + 73728 + bsel * 16384u + wdst + it * 1024);
    }
  };

  STAGE(0, 0);
  unsigned buf = 0;
  for (int ks = 0; ks < 32; ++ks) {
    if (ks < 31) {
      STAGE(buf ^ 1u, ks + 1);
      if (wave < 4) asm volatile("s_waitcnt vmcnt(7)" ::: "memory");
      else          asm volatile("s_waitcnt vmcnt(6)" ::: "memory");
    } else {
      asm volatile("s_waitcnt vmcnt(0)" ::: "memory");
    }
    __builtin_amdgcn_s_barrier();
    unsigned xb = buf * 20480u;
    unsigned w1b = 40960 + buf * 16384u;
    unsigned w3b = 73728 + buf * 16384u;
    bf16x8 af[5];
    #pragma unroll
    for (int mi = 0; mi < 5; ++mi)
      af[mi] = *(const bf16x8*)(smem + xb + offA[mi]);
    #pragma unroll
    for (int ni = 0; ni < 4; ++ni) {
      bf16x8 b1 = cvt8(*(const f32x4*)(smem + w1b + offB[ni][0]),
                       *(const f32x4*)(smem + w1b + offB[ni][1]));
      bf16x8 b3 = cvt8(*(const f32x4*)(smem + w3b + offB[ni][0]),
                       *(const f32x4*)(smem + w3b + offB[ni][1]));
      #pragma unroll
      for (int mi = 0; mi < 5; ++mi) {
        acc1[mi][ni] = __builtin_amdgcn_mfma_f32_16x16x32_bf16(af[mi], b1, acc1[mi][ni], 0, 0, 0);
        acc3[mi][ni] = __builtin_amdgcn_mfma_f32_16x16x32_bf16(af[mi], b3, acc3[mi][ni], 0, 0, 0);
      }
    }
    __builtin_amdgcn_s_barrier();
    buf ^= 1u;
  }

  #pragma unroll
  for (int mi = 0; mi < 5; ++mi) {
    int mb = wm * 80 + mi * 16 + lq * 4;
    #pragma unroll
    for (int r = 0; r < 4; ++r) {
      int lrow = mt * 320 + mb + r;
      if (lrow < Ne) {
        size_t hrow = (size_t)(rbase + lrow) * F_DIM;
        #pragma unroll
        for (int ni = 0; ni < 4; ++ni) {
          int f = nt * 128 + wn * 64 + ni * 16 + lr16;
          float a1v = acc1[mi][ni][r];
          float a3v = acc3[mi][ni][r];
          float hv = (a1v / (1.f + __expf(-a1v))) * a3v;
          H[hrow + f] = f2bf(hv);
        }
      }
    }
  }
}

// ---------------- GEMM2: Y = H @ w2^T (bf16 out)
// BM=320 BN=128 BK=64, 512 thr, 1 block/CU.
// XCD-PINNED 1D grid (256): xcd=bid&7, sub=bid>>3; e=xcd*2+(sub>>4); nt=sub&7; mt=(sub>>3)&1.
// H slice (2.1MB/expert) L2-resident per XCD. Uniform 9 loads/wave, vmcnt(9).
// LDS: A 2x40K @0 | B 2x32K @81920 = 144 KB.
__global__ __launch_bounds__(512, 2) void moe_gemm2(
    const unsigned short* __restrict__ H, const float* __restrict__ w2s,
    const int* __restrict__ cnt, const int* __restrict__ rowbase,
    unsigned short* __restrict__ Ybf)
{
  int bid = blockIdx.x;
  int xcd = bid & 7, sub = bid >> 3;
  int e  = xcd * 2 + (sub >> 4);
  int nt = sub & 7;
  int mt = (sub >> 3) & 1;
  int Ne = cnt[e];
  if (mt * 320 >= Ne) return;
  int rbase = rowbase[e];

  __shared__ char smem[147456];

  int tid = threadIdx.x, lane = tid & 63, wave = tid >> 6;

  // A staging: 40 chunks (8 rows x 128B); wave w: {w, w+8, w+16, w+24, w+32}
  const char* pa[5];
  unsigned aoff[5];
  #pragma unroll
  for (int it = 0; it < 5; ++it) {
    int ch = wave + it * 8;
    int row = ch * 8 + (lane >> 3);
    int grow = mt * 320 + row; if (grow >= Ne) grow = Ne - 1;
    int c8 = (lane & 7) ^ (row & 7);
    pa[it] = (const char*)(H + (size_t)(rbase + grow) * F_DIM) + c8 * 16;
    aoff[it] = (unsigned)(ch * 1024 + lane * 16);
  }

  // B staging: 32 chunks (4 rows x 256B); wave w: {w, w+8, w+16, w+24}
  const float* w2e = w2s + (size_t)e * D_DIM * F_DIM + (size_t)(nt * 128) * F_DIM;
  const char* pb[4];
  unsigned boff[4];
  #pragma unroll
  for (int it = 0; it < 4; ++it) {
    int ch = wave + it * 8;
    int row = ch * 4 + (lane >> 4);
    int c = (lane & 15) ^ (row & 7);
    pb[it] = (const char*)(w2e + (size_t)row * F_DIM) + c * 16;
    boff[it] = (unsigned)(ch * 1024 + lane * 16);
  }

  // wave map: 4M x 2N, wave-tile 80x64
  int wm = wave >> 1, wn = wave & 1;
  int lr16 = lane & 15, lq = lane >> 4;

  f32x4 acc[5][4];
  #pragma unroll
  for (int i = 0; i < 5; ++i)
    #pragma unroll
    for (int j = 0; j < 4; ++j) acc[i][j] = {0.f, 0.f, 0.f, 0.f};

  auto STAGE = [&](unsigned bsel, int ks) {
    #pragma unroll
    for (int it = 0; it < 5; ++it)
      gload16(pa[it] + ks * 128, smem + bsel * 40960u + aoff[it]);
    #pragma unroll
    for (int it = 0; it < 4; ++it)
      gload16(pb[it] + ks * 256, smem + 81920 + bsel * 32768u + boff[it]);
  };

  STAGE(0, 0);
  unsigned buf = 0;
  for (int ks = 0; ks < 64; ++ks) {
    if (ks < 63) {
      STAGE(buf ^ 1u, ks + 1);
      asm volatile("s_waitcnt vmcnt(9)" ::: "memory");
    } else {
      asm volatile("s_waitcnt vmcnt(0)" ::: "memory");
    }
    __builtin_amdgcn_s_barrier();
    unsigned ab = buf * 40960u;
    unsigned bb = 81920 + buf * 32768u;
    #pragma unroll
    for (int ksub = 0; ksub < 2; ++ksub) {
      bf16x8 bfr[4];
      #pragma unroll
      for (int ni = 0; ni < 4; ++ni) {
        int n = wn * 64 + ni * 16 + lr16;
        unsigned o0 = (unsigned)(n * 256 + (((ksub * 8 + lq * 2 + 0) ^ (n & 7)) * 16));
        unsigned o1 = (unsigned)(n * 256 + (((ksub * 8 + lq * 2 + 1) ^ (n & 7)) * 16));
        bfr[ni] = cvt8(*(const f32x4*)(smem + bb + o0), *(const f32x4*)(smem + bb + o1));
      }
      #pragma unroll
      for (int mi = 0; mi < 5; ++mi) {
        int m = wm * 80 + mi * 16 + lr16;
        unsigned off = (unsigned)(m * 128 + (((ksub * 4 + lq) ^ (m & 7)) * 16));
        bf16x8 af = *(const bf16x8*)(smem + ab + off);
        #pragma unroll
        for (int ni = 0; ni < 4; ++ni)
          acc[mi][ni] = __builtin_amdgcn_mfma_f32_16x16x32_bf16(af, bfr[ni], acc[mi][ni], 0, 0, 0);
      }
    }
    __builtin_amdgcn_s_barrier();
    buf ^= 1u;
  }

  #pragma unroll
  for (int mi = 0; mi < 5; ++mi) {
    int mb = wm * 80 + mi * 16 + lq * 4;
    #pragma unroll
    for (int r = 0; r < 4; ++r) {
      int lrow = mt * 320 + mb + r;
      if (lrow < Ne) {
        size_t yrow = (size_t)(rbase + lrow) * D_DIM;
        #pragma unroll
        for (int ni = 0; ni < 4; ++ni) {
          int d = nt * 128 + wn * 64 + ni * 16 + lr16;
          Ybf[yrow + d] = f2bf(acc[mi][ni][r]);
        }
      }
    }
  }
}

// ---------------- combine
__global__ __launch_bounds__(128) void moe_combine(
    const unsigned short* __restrict__ Ybf, const int* __restrict__ rowpos,
    const float* __restrict__ topw, float* __restrict__ out)
{
  int t = blockIdx.x, tid = threadIdx.x;
  int r0 = rowpos[t * 2], r1 = rowpos[t * 2 + 1];
  float p0 = topw[t * 2], p1 = topw[t * 2 + 1];
  uint4 a = ((const uint4*)(Ybf + (size_t)r0 * D_DIM))[tid];
  uint4 b = ((const uint4*)(Ybf + (size_t)r1 * D_DIM))[tid];
  float4 o0, o1;
  #define LO(u) __builtin_bit_cast(float, (unsigned)((u) << 16))
  #define HI(u) __builtin_bit_cast(float, (unsigned)((u) & 0xffff0000u))
  o0.x = p0 * LO(a.x) + p1 * LO(b.x);  o0.y = p0 * HI(a.x) + p1 * HI(b.x);
  o0.z = p0 * LO(a.y) + p1 * LO(b.y);  o0.w = p0 * HI(a.y) + p1 * HI(b.y);
  o1.x = p0 * LO(a.z) + p1 * LO(b.z);  o1.y = p0 * HI(a.z) + p1 * HI(b.z);
  o1.z = p0 * LO(a.w) + p1 * LO(b.w);  o1.w = p0 * HI(a.w) + p1 * HI(b.w);
  #undef LO
  #undef HI
  float4* orow = (float4*)(out + (size_t)t * D_DIM);
  orow[tid * 2]     = o0;
  orow[tid * 2 + 1] = o1;
}

extern "C" void kernel_launch(void* const* d_in, const int* in_sizes, int n_in,
                              void* d_out, int out_size, void* d_ws, size_t ws_size,
                              hipStream_t stream) {
  const float* x    = (const float*)d_in[0];
  const float* gate = (const float*)d_in[1];
  const float* w1   = (const float*)d_in[2];
  const float* w2   = (const float*)d_in[3];
  const float* w3   = (const float*)d_in[4];
  float* out    = (float*)d_out;
  float* logits = out + (size_t)T_NUM * D_DIM;

  char* ws = (char*)d_ws;
  int*   cnt     = (int*)(ws + 0);
  int*   rowbase = (int*)(ws + 64);
  int*   topi    = (int*)(ws + 1024);
  float* topw    = (float*)(ws + 1024 + 16384);
  int*   rowlist = (int*)(ws + 1024 + 32768);
  int*   rowpos  = (int*)(ws + 1024 + 49152);
  unsigned short* H  = (unsigned short*)(ws + 131072);                 // 32 MB
  // xg (6144 rows, 12.6 MB) and Ybf (4096 rows, 8 MB) share one region:
  // xg is dead before gemm2 writes Ybf.
  unsigned short* xg  = (unsigned short*)(ws + 131072 + 33554432);
  unsigned short* Ybf = xg;

  moe_router<<<T_NUM / 16, 256, 0, stream>>>(x, gate, logits, topi, topw);
  moe_route_build<<<1, 1024, 0, stream>>>(topi, cnt, rowbase, rowlist, rowpos);
  moe_gather<<<6144, 256, 0, stream>>>(x, rowlist, rowbase, xg);
  moe_gemm1<<<1024, 512, 0, stream>>>(xg, w1, w3, cnt, rowbase, H);
  moe_gemm2<<<256, 512, 0, stream>>>(H, w2, cnt, rowbase, Ybf);
  moe_combine<<<T_NUM, 128, 0, stream>>>(Ybf, rowpos, topw, out);
}